// Round 11
// baseline (1412.377 us; speedup 1.0000x reference)
//
#include <hip/hip_runtime.h>
#include <hip/hip_bf16.h>
#include <stdint.h>

#define NN 8192
#define EDG 131072
#define NSPLIT 4

typedef __attribute__((ext_vector_type(8))) short bf16x8;
typedef __attribute__((ext_vector_type(4))) float f32x4;
typedef unsigned short us;

__device__ __forceinline__ us f2bf(float f) {
  union { float f; unsigned u; } v; v.f = f;
  return (us)((v.u + 0x7fffu + ((v.u >> 16) & 1u)) >> 16);
}

__device__ __forceinline__ us f2bf_trunc(float f) {
  union { float f; unsigned u; } v; v.f = f;
  return (us)(v.u >> 16);
}

__device__ __forceinline__ float bf2f(us u) {
  union { unsigned u; float f; } v; v.u = ((unsigned)u) << 16;
  return v.f;
}

__device__ __forceinline__ void load_lds16(const void* g, void* l) {
  __builtin_amdgcn_global_load_lds(
      (__attribute__((address_space(1))) void*)(uintptr_t)g,
      (__attribute__((address_space(3))) void*)(uintptr_t)l,
      16, 0, 0);
}

// ---------------------------------------------------------------------------
// C[M,N] = A[M,K]*Bt[N,K]^T, 64x128 tile, wave-per-16-rows. grid=(M/64,N/128).
// EPI 0: fp32; 2: fp32 +bias[col]; 4: bf16 +bias[col]; 5: bf16 tanh(+bias);
//     6: bf16 v*bias[row]  (row-scaled store, bias = rscale)
// ---------------------------------------------------------------------------
template <int EPI>
__global__ __launch_bounds__(256) void gemm_k(
    const us* __restrict__ A, int lda, const us* __restrict__ Bt, int ldb,
    const float* __restrict__ bias, void* __restrict__ Cv, int ldc, int K) {
  __shared__ alignas(16) us As[64 * 32];
  __shared__ alignas(16) us Bs[128 * 32];
  const int t = threadIdx.x;
  const int wave = t >> 6, lane = t & 63;
  const int wrow = wave * 16;
  const int lrow = lane & 15, quad = lane >> 4;
  const int rowBase = blockIdx.x * 64;
  const int colBase = blockIdx.y * 128;
  const int sr = t >> 2, sch = t & 3;

  f32x4 acc[8];
#pragma unroll
  for (int j = 0; j < 8; j++) acc[j] = f32x4{0.f, 0.f, 0.f, 0.f};

  for (int kb = 0; kb < K; kb += 32) {
    __syncthreads();
    const us* asrc = A + (size_t)(rowBase + sr) * lda + kb + sch * 8;
    load_lds16(asrc, (char*)As + t * 16);
    const us* bsrc = Bt + (size_t)(colBase + sr) * ldb + kb + sch * 8;
    load_lds16(bsrc, (char*)Bs + t * 16);
    load_lds16(bsrc + (size_t)64 * ldb, (char*)Bs + t * 16 + 4096);
    __syncthreads();
    bf16x8 af = *(const bf16x8*)&As[(wrow + lrow) * 32 + quad * 8];
#pragma unroll
    for (int j = 0; j < 8; j++) {
      bf16x8 bfr = *(const bf16x8*)&Bs[(j * 16 + lrow) * 32 + quad * 8];
      acc[j] = __builtin_amdgcn_mfma_f32_16x16x32_bf16(af, bfr, acc[j], 0, 0, 0);
    }
  }

#pragma unroll
  for (int j = 0; j < 8; j++) {
    int col = colBase + j * 16 + lrow;
#pragma unroll
    for (int r = 0; r < 4; r++) {
      int row = rowBase + wrow + quad * 4 + r;
      size_t idx = (size_t)row * ldc + col;
      float v = acc[j][r];
      if (EPI == 0) ((float*)Cv)[idx] = v;
      else if (EPI == 2) ((float*)Cv)[idx] = v + bias[col];
      else if (EPI == 4) ((us*)Cv)[idx] = f2bf(v + bias[col]);
      else if (EPI == 5) ((us*)Cv)[idx] = f2bf(tanhf(v + bias[col]));
      else ((us*)Cv)[idx] = f2bf(v * bias[row]);
    }
  }
}

// ---------------------------------------------------------------------------
// Flash attention, 2x2 wave tiling (wave = 32 rows x 128 cols) to cut LDS
// read traffic 1.7x (10 b128-reads per 16 MFMA instead of 17).
// Q[NN][DIN],K[NN][DIN] bf16; Vt[DIN][NN] bf16. grid=(NN/64, NSPLIT).
// Ps (64x256, 32 KB) aliases the K double-buffer. LDS 73/57 KB -> 2 blk/CU.
// ---------------------------------------------------------------------------
template <int DIN>
__global__ __launch_bounds__(256, 2) void flash_att(
    const us* __restrict__ Q, const us* __restrict__ K,
    const us* __restrict__ Vt, us* __restrict__ Opart,
    float* __restrict__ mpart, float* __restrict__ lpart, int kvPerSplit) {
  constexpr int NKC = DIN / 32;   // S-phase k chunks
  constexpr int OJ = DIN / 32;    // PV col tiles per wave (DIN/2 cols)
  __shared__ alignas(16) us As[2][64 * 32];    // Q dbuf (8 KB)
  __shared__ alignas(16) us KB[2][256 * 32];   // K dbuf (32 KB); Ps alias
  __shared__ alignas(16) us Vs[2][DIN * 32];   // V dbuf (32/16 KB)
  __shared__ float redM[2][64];
  __shared__ float redL[2][64];
  us* Ps = &KB[0][0];                          // 64 x 256

  const int t = threadIdx.x;
  const int wave = t >> 6, lane = t & 63;
  const int wr = wave >> 1;        // row half: rows wr*32 .. +32
  const int wc = wave & 1;         // col half
  const int lrow = lane & 15, quad = lane >> 4;
  const int rowBase = blockIdx.x * 64;
  const int split = blockIdx.y;
  const int kv0 = split * kvPerSplit;
  const int sr = t >> 2, sch = t & 3;
  const int pkey = ((lrow >> 2) ^ lrow) & 3;

  auto stageQ = [&](int kc, int buf) {
    const us* qsrc = Q + (size_t)(rowBase + sr) * DIN + kc * 32 + sch * 8;
    load_lds16(qsrc, (char*)&As[buf][0] + t * 16);
  };
  auto stageK = [&](int kt, int kc, int buf) {  // 256 kv rows x 32 k
    const us* ksrc = K + (size_t)(kt + sr) * DIN + kc * 32 + sch * 8;
#pragma unroll
    for (int p = 0; p < 4; p++)
      load_lds16(ksrc + (size_t)(p * 64) * DIN, (char*)&KB[buf][0] + p * 4096 + t * 16);
  };
  auto stageV = [&](int kt, int cc, int buf) {  // DIN rows x 32 kv
#pragma unroll
    for (int p = 0; p < DIN / 64; p++) {
      const us* vsrc = Vt + (size_t)(p * 64 + sr) * NN + kt + cc * 32 + sch * 8;
      load_lds16(vsrc, (char*)&Vs[buf][0] + p * 4096 + t * 16);
    }
  };

  stageQ(0, 0);
  stageV(kv0, 0, 0);

  float m_i[8], l_i[8];  // x = i*4 + r; row64 = wr*32 + i*16 + quad*4 + r
#pragma unroll
  for (int x = 0; x < 8; x++) { m_i[x] = -3.0e38f; l_i[x] = 0.f; }
  f32x4 accO[2][OJ];
#pragma unroll
  for (int i = 0; i < 2; i++)
#pragma unroll
    for (int j = 0; j < OJ; j++) accO[i][j] = f32x4{0.f, 0.f, 0.f, 0.f};

  for (int kt = kv0; kt < kv0 + kvPerSplit; kt += 256) {
    __syncthreads();                 // E: all PV reads of Ps (KB) done
    stageK(kt, 0, 0);

    // ---- Phase 1: S(64x256) = Q @ K^T ; wave: 32 rows x 128 cols ----
    f32x4 accS[2][8];
#pragma unroll
    for (int i = 0; i < 2; i++)
#pragma unroll
      for (int j = 0; j < 8; j++) accS[i][j] = f32x4{0.f, 0.f, 0.f, 0.f};
    for (int kc = 0; kc < NKC; kc++) {
      const int buf = kc & 1;
      __syncthreads();               // drain Q/K chunk kc
      if (kc + 1 < NKC) { stageK(kt, kc + 1, buf ^ 1); stageQ(kc + 1, buf ^ 1); }
      bf16x8 af[2];
#pragma unroll
      for (int i = 0; i < 2; i++)
        af[i] = *(const bf16x8*)&As[buf][(wr * 32 + i * 16 + lrow) * 32 + quad * 8];
#pragma unroll
      for (int j = 0; j < 8; j++) {
        bf16x8 bfr = *(const bf16x8*)&KB[buf][(wc * 128 + j * 16 + lrow) * 32 + quad * 8];
#pragma unroll
        for (int i = 0; i < 2; i++)
          accS[i][j] = __builtin_amdgcn_mfma_f32_16x16x32_bf16(af[i], bfr, accS[i][j], 0, 0, 0);
      }
    }

    // ---- Phase 2: online softmax, cross-wave (col halves) via redM/redL ----
    float tm[8];
#pragma unroll
    for (int i = 0; i < 2; i++)
#pragma unroll
      for (int r = 0; r < 4; r++) {
        float v = accS[i][0][r];
#pragma unroll
        for (int j = 1; j < 8; j++) v = fmaxf(v, accS[i][j][r]);
#pragma unroll
        for (int mask = 1; mask < 16; mask <<= 1) v = fmaxf(v, __shfl_xor(v, mask));
        tm[i * 4 + r] = v;
      }
    if (lrow == 0) {
#pragma unroll
      for (int i = 0; i < 2; i++)
#pragma unroll
        for (int r = 0; r < 4; r++)
          redM[wc][wr * 32 + i * 16 + quad * 4 + r] = tm[i * 4 + r];
    }
    __syncthreads();                 // B1: redM visible; KB reads done -> Ps ok
    float alpha[8];
#pragma unroll
    for (int i = 0; i < 2; i++)
#pragma unroll
      for (int r = 0; r < 4; r++) {
        int x = i * 4 + r, row = wr * 32 + i * 16 + quad * 4 + r;
        float mt = fmaxf(redM[0][row], redM[1][row]);
        float mn = fmaxf(m_i[x], mt);
        alpha[x] = __expf(m_i[x] - mn);
        m_i[x] = mn;
      }
    float ts[8];
#pragma unroll
    for (int x = 0; x < 8; x++) ts[x] = 0.f;
#pragma unroll
    for (int i = 0; i < 2; i++)
#pragma unroll
      for (int j = 0; j < 8; j++)
#pragma unroll
        for (int r = 0; r < 4; r++) {
          int x = i * 4 + r;
          float p = __expf(accS[i][j][r] - m_i[x]);
          ts[x] += p;
          int prow = wr * 32 + i * 16 + quad * 4 + r;
          int key = (quad ^ r) & 3;
          int g = 2 * (wc * 8 + j) + (lrow >> 3);
          Ps[prow * 256 + ((g ^ (key << 1)) << 3) + (lrow & 7)] = f2bf_trunc(p);
        }
#pragma unroll
    for (int x = 0; x < 8; x++) {
#pragma unroll
      for (int mask = 1; mask < 16; mask <<= 1) ts[x] += __shfl_xor(ts[x], mask);
    }
    if (lrow == 0) {
#pragma unroll
      for (int i = 0; i < 2; i++)
#pragma unroll
        for (int r = 0; r < 4; r++)
          redL[wc][wr * 32 + i * 16 + quad * 4 + r] = ts[i * 4 + r];
    }
    // rescale O while redL propagates
#pragma unroll
    for (int i = 0; i < 2; i++)
#pragma unroll
      for (int j = 0; j < OJ; j++)
#pragma unroll
        for (int r = 0; r < 4; r++) accO[i][j][r] *= alpha[i * 4 + r];
    __syncthreads();                 // B2: Ps + redL + V0 drained
#pragma unroll
    for (int i = 0; i < 2; i++)
#pragma unroll
      for (int r = 0; r < 4; r++) {
        int x = i * 4 + r, row = wr * 32 + i * 16 + quad * 4 + r;
        l_i[x] = l_i[x] * alpha[x] + redL[0][row] + redL[1][row];
      }

    // ---- Phase 3: O += P @ V ; wave: 32 rows x DIN/2 cols; V dbuf ----
    const bool hasNext = (kt + 256 < kv0 + kvPerSplit);
    for (int cc = 0; cc < 8; cc++) {
      if (cc) __syncthreads();       // drain V[cc]
      if (cc + 1 < 8) stageV(kt, cc + 1, (cc + 1) & 1);
      else if (hasNext) { stageV(kt + 256, 0, 0); stageQ(0, 0); }
      const int gk = cc * 4 + quad;
      bf16x8 af[2];
#pragma unroll
      for (int i = 0; i < 2; i++)
        af[i] = *(const bf16x8*)&Ps[(wr * 32 + i * 16 + lrow) * 256 + ((gk ^ (pkey << 1)) << 3)];
      const us* vb = &Vs[cc & 1][0];
#pragma unroll
      for (int j = 0; j < OJ; j++) {
        bf16x8 bfr = *(const bf16x8*)&vb[(wc * (DIN / 2) + j * 16 + lrow) * 32 + quad * 8];
#pragma unroll
        for (int i = 0; i < 2; i++)
          accO[i][j] = __builtin_amdgcn_mfma_f32_16x16x32_bf16(af[i], bfr, accO[i][j], 0, 0, 0);
      }
    }
  }

  // ---- epilogue: un-normalized partials ----
#pragma unroll
  for (int i = 0; i < 2; i++)
#pragma unroll
    for (int j = 0; j < OJ; j++)
#pragma unroll
      for (int r = 0; r < 4; r++) {
        int row = rowBase + wr * 32 + i * 16 + quad * 4 + r;
        int col = wc * (DIN / 2) + j * 16 + lrow;
        Opart[((size_t)split * NN + row) * DIN + col] = f2bf(accO[i][j][r]);
      }
  if (lrow == 0 && wc == 0) {
#pragma unroll
    for (int i = 0; i < 2; i++)
#pragma unroll
      for (int r = 0; r < 4; r++) {
        int row = rowBase + wr * 32 + i * 16 + quad * 4 + r;
        mpart[(size_t)split * NN + row] = m_i[i * 4 + r];
        lpart[(size_t)split * NN + row] = l_i[i * 4 + r];
      }
  }
}

// fused: merge NSPLIT flash partials + build cat = bf16([c | f | f-att])
__global__ void merge_cat(const us* __restrict__ Op, const float* __restrict__ mp,
                          const float* __restrict__ lp, const us* __restrict__ cbuf,
                          const us* __restrict__ fbf, us* __restrict__ cat,
                          int din, int W) {
  int i = blockIdx.y;
  int c = blockIdx.x * 256 + threadIdx.x;
  us o;
  if (c < 256) {
    o = cbuf[(size_t)i * 256 + c];
  } else if (c < 256 + din) {
    o = fbf[(size_t)i * din + (c - 256)];
  } else {
    int f = c - 256 - din;
    float m[NSPLIT], w[NSPLIT];
    float M = -3.0e38f;
#pragma unroll
    for (int s = 0; s < NSPLIT; s++) { m[s] = mp[(size_t)s * NN + i]; M = fmaxf(M, m[s]); }
    float L = 0.f;
#pragma unroll
    for (int s = 0; s < NSPLIT; s++) { w[s] = __expf(m[s] - M); L += lp[(size_t)s * NN + i] * w[s]; }
    float a = 0.f;
#pragma unroll
    for (int s = 0; s < NSPLIT; s++)
      a += w[s] * bf2f(Op[((size_t)s * NN + i) * din + f]);
    o = f2bf(bf2f(fbf[(size_t)i * din + f]) - a / L);
  }
  cat[(size_t)i * W + c] = o;
}

// --------------------------- small kernels ---------------------------------

__global__ void ws_sentinel(float* out) { out[0] = 12345.0f; out[1] = 12345.0f; }

__global__ void cvt_bf16(const float* __restrict__ in, us* __restrict__ out, int n) {
  int i = (blockIdx.x * 256 + threadIdx.x) * 4;
  if (i < n) {
    f32x4 v = *(const f32x4*)(in + i);
    uint2 p;
    p.x = f2bf(v.x) | ((unsigned)f2bf(v.y) << 16);
    p.y = f2bf(v.z) | ((unsigned)f2bf(v.w) << 16);
    *(uint2*)(out + i) = p;
  }
}

// dst[C][R] = bf16(src[R][C]), fp32 source
__global__ void transpose_bf16(const float* __restrict__ src, us* __restrict__ dst,
                               int R, int C) {
  __shared__ float tile[32][33];
  int c0 = blockIdx.x * 32, r0 = blockIdx.y * 32;
  int x = threadIdx.x, y = threadIdx.y;
  for (int i = y; i < 32; i += 8) tile[i][x] = src[(size_t)(r0 + i) * C + c0 + x];
  __syncthreads();
  for (int i = y; i < 32; i += 8) dst[(size_t)(c0 + i) * R + r0 + x] = f2bf(tile[x][i]);
}

// dst[C][R] = src[R][C], bf16 source
__global__ void transpose_bb(const us* __restrict__ src, us* __restrict__ dst,
                             int R, int C) {
  __shared__ us tile[32][33];
  int c0 = blockIdx.x * 32, r0 = blockIdx.y * 32;
  int x = threadIdx.x, y = threadIdx.y;
  for (int i = y; i < 32; i += 8) tile[i][x] = src[(size_t)(r0 + i) * C + c0 + x];
  __syncthreads();
  for (int i = y; i < 32; i += 8) dst[(size_t)(c0 + i) * R + r0 + x] = tile[x][i];
}

__global__ void deg_count(const int* __restrict__ dst, int* __restrict__ deg) {
  int e = blockIdx.x * 256 + threadIdx.x;
  atomicAdd(&deg[dst[e]], 1);
}

__global__ void make_dinv(const int* __restrict__ deg, float* __restrict__ dinv) {
  int v = blockIdx.x * 256 + threadIdx.x;
  dinv[v] = rsqrtf((float)(deg[v] + 1));
}

__global__ void scan_deg(const int* __restrict__ deg, int* __restrict__ rowstart) {
  __shared__ int part[1024];
  int t = threadIdx.x;
  int base = t * 8;
  int local[8];
  int s = 0;
#pragma unroll
  for (int i = 0; i < 8; i++) { local[i] = s; s += deg[base + i]; }
  part[t] = s;
  __syncthreads();
  for (int off = 1; off < 1024; off <<= 1) {
    int v = (t >= off) ? part[t - off] : 0;
    __syncthreads();
    part[t] += v;
    __syncthreads();
  }
  int offset = (t == 0) ? 0 : part[t - 1];
#pragma unroll
  for (int i = 0; i < 8; i++) rowstart[base + i] = offset + local[i];
  if (t == 1023) rowstart[8192] = offset + s;
}

__global__ void csr_fill(const int* __restrict__ src, const int* __restrict__ dst,
                         int* __restrict__ cursor, int* __restrict__ csr_src) {
  int e = blockIdx.x * 256 + threadIdx.x;
  int pos = atomicAdd(&cursor[dst[e]], 1);
  csr_src[pos] = src[e];
}

// c[v] = bf16( dinv[v] * (hs[v] + sum_in hs[s]) ), hs = bf16(dinv.*h), bf16 gather
__global__ __launch_bounds__(256) void gcn_agg_b(
    const int* __restrict__ rowstart, const int* __restrict__ csr_src,
    const float* __restrict__ dinv, const us* __restrict__ hs,
    us* __restrict__ c) {
  int node = blockIdx.x * 4 + (threadIdx.x >> 6);
  int lane = threadIdx.x & 63;
  const us* hp = hs + lane * 4;
  uint2 u = *(const uint2*)(hp + (size_t)node * 256);
  float a0 = bf2f(u.x & 0xffffu), a1 = bf2f(u.x >> 16);
  float a2 = bf2f(u.y & 0xffffu), a3 = bf2f(u.y >> 16);
  int s0 = rowstart[node], s1 = rowstart[node + 1];
  for (int j = s0; j < s1; j++) {
    int s = csr_src[j];
    uint2 v = *(const uint2*)(hp + (size_t)s * 256);
    a0 += bf2f(v.x & 0xffffu); a1 += bf2f(v.x >> 16);
    a2 += bf2f(v.y & 0xffffu); a3 += bf2f(v.y >> 16);
  }
  float dn = dinv[node];
  uint2 o;
  o.x = f2bf(a0 * dn) | ((unsigned)f2bf(a1 * dn) << 16);
  o.y = f2bf(a2 * dn) | ((unsigned)f2bf(a3 * dn) << 16);
  *(uint2*)(c + (size_t)node * 256 + lane * 4) = o;
}

__global__ void gated_pool(const float* __restrict__ q, const us* __restrict__ f,
                           float* __restrict__ p) {
  int col = threadIdx.x;
  int r0 = blockIdx.x * 128;
  float a = 0.f;
  for (int i = r0; i < r0 + 128; i++) {
    float qv = q[(size_t)i * 256 + col];
    a += bf2f(f[(size_t)i * 256 + col]) / (1.f + __expf(-qv));
  }
  atomicAdd(&p[col], a);
}

__global__ void ntn_bilinear(const float* __restrict__ p1, const float* __restrict__ tnW,
                             float* __restrict__ tmp) {
  int c = blockIdx.x * 256 + threadIdx.x;
  float a = 0.f;
#pragma unroll 8
  for (int i = 0; i < 256; i++) a += p1[i] * tnW[(size_t)i * 8192 + c];
  tmp[c] = a;
}

__global__ void ntn_final(const float* __restrict__ tmp, const float* __restrict__ p1,
                          const float* __restrict__ p2, const float* __restrict__ tnWb,
                          const float* __restrict__ tnb, const float* __restrict__ fc1W,
                          const float* __restrict__ fc1b, const float* __restrict__ scW,
                          const float* __restrict__ scb, const float* __restrict__ avgv,
                          float* __restrict__ out) {
  __shared__ float pc[512];
  __shared__ float ntn[32];
  __shared__ float sarr[16];
  int t = threadIdx.x;
  pc[t] = p1[t];
  pc[256 + t] = p2[t];
  __syncthreads();
  if (t < 32) {
    float sc = 0.f;
    for (int j = 0; j < 256; j++) sc += tmp[j * 32 + t] * pc[256 + j];
    float bl = 0.f;
    for (int k = 0; k < 512; k++) bl += tnWb[t * 512 + k] * pc[k];
    float v = sc + bl + tnb[t];
    ntn[t] = v > 0.f ? v : 0.f;
  }
  __syncthreads();
  if (t < 16) {
    float a = fc1b[t];
    for (int i = 0; i < 32; i++) a += ntn[i] * fc1W[i * 16 + t];
    sarr[t] = tanhf(a);
  }
  __syncthreads();
  if (t == 0) {
    float a = scb[0];
    for (int b = 0; b < 16; b++) a += sarr[b] * scW[b];
    float score = 1.f / (1.f + expf(-a));
    out[0] = score;
    out[1] = -logf(score) * avgv[0];
  }
}

// ---------------------------------------------------------------------------

extern "C" void kernel_launch(void* const* d_in, const int* in_sizes, int n_in,
                              void* d_out, int out_size, void* d_ws, size_t ws_size,
                              hipStream_t stream) {
  (void)in_sizes; (void)n_in; (void)out_size;
  const float* feat1 = (const float*)d_in[0];
  const float* feat2 = (const float*)d_in[1];
  const int* ei1 = (const int*)d_in[2];
  const int* ei2 = (const int*)d_in[3];
  const float* avgv = (const float*)d_in[4];
  const float* gcnW[3] = {(const float*)d_in[5], (const float*)d_in[8], (const float*)d_in[11]};
  const float* updW[3] = {(const float*)d_in[6], (const float*)d_in[9], (const float*)d_in[12]};
  const float* updb[3] = {(const float*)d_in[7], (const float*)d_in[10], (const float*)d_in[13]};
  const float* gatedW = (const float*)d_in[14];
  const float* gatedb = (const float*)d_in[15];
  const float* tnW = (const float*)d_in[16];
  const float* tnWb = (const float*)d_in[17];
  const float* tnb = (const float*)d_in[18];
  const float* fc1W = (const float*)d_in[19];
  const float* fc1b = (const float*)d_in[20];
  const float* scW = (const float*)d_in[21];
  const float* scb = (const float*)d_in[22];
  float* out = (float*)d_out;

  char* wp = (char*)d_ws;
  auto take = [&](size_t b) { char* p = wp; wp += (b + 255) & ~(size_t)255; return p; };
  us* Op = (us*)take((size_t)NSPLIT * NN * 256 * 2);           // 16 MB
  us* cat1 = (us*)take((size_t)NN * 768 * 2);
  us* cat2 = (us*)take((size_t)NN * 768 * 2);
  us* fA1 = (us*)take((size_t)NN * 256 * 2);
  us* fA2 = (us*)take((size_t)NN * 256 * 2);
  us* fB1 = (us*)take((size_t)NN * 256 * 2);
  us* fB2 = (us*)take((size_t)NN * 256 * 2);
  us* f1bT = (us*)take((size_t)NN * 256 * 2);
  us* f2bT = (us*)take((size_t)NN * 256 * 2);
  us* hs1 = (us*)take((size_t)NN * 256 * 2);
  us* hs2 = (us*)take((size_t)NN * 256 * 2);
  us* cb1 = (us*)take((size_t)NN * 256 * 2);
  us* cb2 = (us*)take((size_t)NN * 256 * 2);
  float* q1 = (float*)take((size_t)NN * 256 * 4);
  float* q2 = (float*)take((size_t)NN * 256 * 4);
  us* WgT[3], *WuT[3];
  for (int l = 0; l < 3; l++) WgT[l] = (us*)take(256 * 256 * 2);
  for (int l = 0; l < 3; l++) WuT[l] = (us*)take(256 * 768 * 2);
  us* gWT = (us*)take(256 * 256 * 2);
  int* deg1 = (int*)take(NN * 4);
  int* deg2 = (int*)take(NN * 4);
  float* dinv1 = (float*)take(NN * 4);
  float* dinv2 = (float*)take(NN * 4);
  int* rs1 = (int*)take((NN + 1) * 4);
  int* rs2 = (int*)take((NN + 1) * 4);
  int* cur1 = (int*)take(NN * 4);
  int* cur2 = (int*)take(NN * 4);
  int* csr1 = (int*)take((size_t)EDG * 4);
  int* csr2 = (int*)take((size_t)EDG * 4);
  float* mp = (float*)take((size_t)NSPLIT * NN * 4);
  float* lp = (float*)take((size_t)NSPLIT * NN * 4);
  float* p1 = (float*)take(1024);
  float* p2 = (float*)take(1024);
  float* tmp = (float*)take(NN * 4);

  size_t need = (size_t)(wp - (char*)d_ws);
  if (need > ws_size) {
    ws_sentinel<<<1, 1, 0, stream>>>(out);
    return;
  }

  // degree / dinv / CSR (edge structure is layer-invariant)
  hipMemsetAsync(deg1, 0, NN * 4, stream);
  hipMemsetAsync(deg2, 0, NN * 4, stream);
  deg_count<<<EDG / 256, 256, 0, stream>>>(ei1 + EDG, deg1);
  deg_count<<<EDG / 256, 256, 0, stream>>>(ei2 + EDG, deg2);
  make_dinv<<<NN / 256, 256, 0, stream>>>(deg1, dinv1);
  make_dinv<<<NN / 256, 256, 0, stream>>>(deg2, dinv2);
  scan_deg<<<1, 1024, 0, stream>>>(deg1, rs1);
  scan_deg<<<1, 1024, 0, stream>>>(deg2, rs2);
  hipMemcpyAsync(cur1, rs1, NN * 4, hipMemcpyDeviceToDevice, stream);
  hipMemcpyAsync(cur2, rs2, NN * 4, hipMemcpyDeviceToDevice, stream);
  csr_fill<<<EDG / 256, 256, 0, stream>>>(ei1, ei1 + EDG, cur1, csr1);
  csr_fill<<<EDG / 256, 256, 0, stream>>>(ei2, ei2 + EDG, cur2, csr2);

  // weights -> bf16 [out][in]
  for (int l = 0; l < 3; l++) {
    int din = (l == 0) ? 128 : 256;
    int W = 256 + 2 * din;
    transpose_bf16<<<dim3(8, din / 32), dim3(32, 8), 0, stream>>>(gcnW[l], WgT[l], din, 256);
    transpose_bf16<<<dim3(8, W / 32), dim3(32, 8), 0, stream>>>(updW[l], WuT[l], W, 256);
  }
  transpose_bf16<<<dim3(8, 8), dim3(32, 8), 0, stream>>>(gatedW, gWT, 256, 256);

  // f (bf16) ping-pong
  us* f1 = fA1; us* f2 = fA2;
  us* fn1 = fB1; us* fn2 = fB2;
  cvt_bf16<<<NN * 128 / 1024, 256, 0, stream>>>(feat1, f1, NN * 128);
  cvt_bf16<<<NN * 128 / 1024, 256, 0, stream>>>(feat2, f2, NN * 128);

  for (int l = 0; l < 3; l++) {
    const int din = (l == 0) ? 128 : 256;
    const int W = 256 + 2 * din;

    if (l == 0) {
      transpose_bf16<<<dim3(din / 32, NN / 32), dim3(32, 8), 0, stream>>>(feat1, f1bT, NN, din);
      transpose_bf16<<<dim3(din / 32, NN / 32), dim3(32, 8), 0, stream>>>(feat2, f2bT, NN, din);
    } else {
      transpose_bb<<<dim3(din / 32, NN / 32), dim3(32, 8), 0, stream>>>(f1, f1bT, NN, din);
      transpose_bb<<<dim3(din / 32, NN / 32), dim3(32, 8), 0, stream>>>(f2, f2bT, NN, din);
    }

    // hs = bf16(dinv .* (f @ Wg))
    gemm_k<6><<<dim3(128, 2), 256, 0, stream>>>(f1, din, WgT[l], din, dinv1, hs1, 256, din);
    gemm_k<6><<<dim3(128, 2), 256, 0, stream>>>(f2, din, WgT[l], din, dinv2, hs2, 256, din);

    // c = bf16( dinv .* (hs + gather-sum) )
    gcn_agg_b<<<NN / 4, 256, 0, stream>>>(rs1, csr1, dinv1, hs1, cb1);
    gcn_agg_b<<<NN / 4, 256, 0, stream>>>(rs2, csr2, dinv2, hs2, cb2);

    // att1 = Flash(Q=f1,K=f2,V=f2) -> fused merge+cat; then att2 reuses Op
    if (l == 0) {
      flash_att<128><<<dim3(NN / 64, NSPLIT), 256, 0, stream>>>(f1, f2, f2bT, Op, mp, lp, NN / NSPLIT);
      merge_cat<<<dim3(W / 256, NN), 256, 0, stream>>>(Op, mp, lp, cb1, f1, cat1, din, W);
      flash_att<128><<<dim3(NN / 64, NSPLIT), 256, 0, stream>>>(f2, f1, f1bT, Op, mp, lp, NN / NSPLIT);
      merge_cat<<<dim3(W / 256, NN), 256, 0, stream>>>(Op, mp, lp, cb2, f2, cat2, din, W);
    } else {
      flash_att<256><<<dim3(NN / 64, NSPLIT), 256, 0, stream>>>(f1, f2, f2bT, Op, mp, lp, NN / NSPLIT);
      merge_cat<<<dim3(W / 256, NN), 256, 0, stream>>>(Op, mp, lp, cb1, f1, cat1, din, W);
      flash_att<256><<<dim3(NN / 64, NSPLIT), 256, 0, stream>>>(f2, f1, f1bT, Op, mp, lp, NN / NSPLIT);
      merge_cat<<<dim3(W / 256, NN), 256, 0, stream>>>(Op, mp, lp, cb2, f2, cat2, din, W);
    }

    // g = tanh?(cat @ Wu + bu) -> bf16 directly
    if (l < 2) {
      gemm_k<5><<<dim3(128, 2), 256, 0, stream>>>(cat1, W, WuT[l], W, updb[l], fn1, 256, W);
      gemm_k<5><<<dim3(128, 2), 256, 0, stream>>>(cat2, W, WuT[l], W, updb[l], fn2, 256, W);
    } else {
      gemm_k<4><<<dim3(128, 2), 256, 0, stream>>>(cat1, W, WuT[l], W, updb[l], fn1, 256, W);
      gemm_k<4><<<dim3(128, 2), 256, 0, stream>>>(cat2, W, WuT[l], W, updb[l], fn2, 256, W);
    }
    us* s;
    s = f1; f1 = fn1; fn1 = s;
    s = f2; f2 = fn2; fn2 = s;
  }

  // gated readout: q = f@gW+gb (fp32), p = sum sigmoid(q)*f
  gemm_k<2><<<dim3(128, 2), 256, 0, stream>>>(f1, 256, gWT, 256, gatedb, q1, 256, 256);
  gemm_k<2><<<dim3(128, 2), 256, 0, stream>>>(f2, 256, gWT, 256, gatedb, q2, 256, 256);
  hipMemsetAsync(p1, 0, 256 * 4, stream);
  hipMemsetAsync(p2, 0, 256 * 4, stream);
  gated_pool<<<64, 256, 0, stream>>>(q1, f1, p1);
  gated_pool<<<64, 256, 0, stream>>>(q2, f2, p2);

  // NTN + scoring head
  ntn_bilinear<<<32, 256, 0, stream>>>(p1, tnW, tmp);
  ntn_final<<<1, 256, 0, stream>>>(tmp, p1, p2, tnWb, tnb, fc1W, fc1b, scW, scb, avgv, out);
}

// Round 13
// 1073.218 us; speedup vs baseline: 1.3160x; 1.3160x over previous
//
#include <hip/hip_runtime.h>
#include <hip/hip_bf16.h>
#include <stdint.h>

#define NN 8192
#define EDG 131072
#define NSPLIT 4

typedef __attribute__((ext_vector_type(8))) short bf16x8;
typedef __attribute__((ext_vector_type(4))) float f32x4;
typedef unsigned short us;

__device__ __forceinline__ us f2bf(float f) {
  union { float f; unsigned u; } v; v.f = f;
  return (us)((v.u + 0x7fffu + ((v.u >> 16) & 1u)) >> 16);
}

__device__ __forceinline__ us f2bf_trunc(float f) {
  union { float f; unsigned u; } v; v.f = f;
  return (us)(v.u >> 16);
}

__device__ __forceinline__ float bf2f(us u) {
  union { unsigned u; float f; } v; v.u = ((unsigned)u) << 16;
  return v.f;
}

__device__ __forceinline__ void load_lds16(const void* g, void* l) {
  __builtin_amdgcn_global_load_lds(
      (__attribute__((address_space(1))) void*)(uintptr_t)g,
      (__attribute__((address_space(3))) void*)(uintptr_t)l,
      16, 0, 0);
}

// ---------------------------------------------------------------------------
// Pair-fused GEMM: z=0 -> (A1,b1,C1), z=1 -> (A2,b2,C2). 64x128 tile,
// wave-per-16-rows. grid=(M/64, N/128, 2).
// EPI 0: fp32; 2: fp32 +bias[col]; 4: bf16 +bias[col]; 5: bf16 tanh(+bias);
//     6: bf16 v*bias[row]
// ---------------------------------------------------------------------------
template <int EPI>
__global__ __launch_bounds__(256) void gemm2(
    const us* __restrict__ A1, const us* __restrict__ A2, int lda,
    const us* __restrict__ Bt, int ldb,
    const float* __restrict__ b1, const float* __restrict__ b2,
    void* __restrict__ C1, void* __restrict__ C2, int ldc, int K) {
  __shared__ alignas(16) us As[64 * 32];
  __shared__ alignas(16) us Bs[128 * 32];
  const us* A = blockIdx.z ? A2 : A1;
  const float* bias = blockIdx.z ? b2 : b1;
  void* Cv = blockIdx.z ? C2 : C1;
  const int t = threadIdx.x;
  const int wave = t >> 6, lane = t & 63;
  const int wrow = wave * 16;
  const int lrow = lane & 15, quad = lane >> 4;
  const int rowBase = blockIdx.x * 64;
  const int colBase = blockIdx.y * 128;
  const int sr = t >> 2, sch = t & 3;

  f32x4 acc[8];
#pragma unroll
  for (int j = 0; j < 8; j++) acc[j] = f32x4{0.f, 0.f, 0.f, 0.f};

  for (int kb = 0; kb < K; kb += 32) {
    __syncthreads();
    const us* asrc = A + (size_t)(rowBase + sr) * lda + kb + sch * 8;
    load_lds16(asrc, (char*)As + t * 16);
    const us* bsrc = Bt + (size_t)(colBase + sr) * ldb + kb + sch * 8;
    load_lds16(bsrc, (char*)Bs + t * 16);
    load_lds16(bsrc + (size_t)64 * ldb, (char*)Bs + t * 16 + 4096);
    __syncthreads();
    bf16x8 af = *(const bf16x8*)&As[(wrow + lrow) * 32 + quad * 8];
#pragma unroll
    for (int j = 0; j < 8; j++) {
      bf16x8 bfr = *(const bf16x8*)&Bs[(j * 16 + lrow) * 32 + quad * 8];
      acc[j] = __builtin_amdgcn_mfma_f32_16x16x32_bf16(af, bfr, acc[j], 0, 0, 0);
    }
  }

#pragma unroll
  for (int j = 0; j < 8; j++) {
    int col = colBase + j * 16 + lrow;
#pragma unroll
    for (int r = 0; r < 4; r++) {
      int row = rowBase + wrow + quad * 4 + r;
      size_t idx = (size_t)row * ldc + col;
      float v = acc[j][r];
      if (EPI == 0) ((float*)Cv)[idx] = v;
      else if (EPI == 2) ((float*)Cv)[idx] = v + bias[col];
      else if (EPI == 4) ((us*)Cv)[idx] = f2bf(v + bias[col]);
      else if (EPI == 5) ((us*)Cv)[idx] = f2bf(tanhf(v + bias[col]));
      else ((us*)Cv)[idx] = f2bf(v * bias[row]);
    }
  }
}

// ---------------------------------------------------------------------------
// Flash attention (round-9 proven body), both directions fused via blockIdx.z:
//   z=0: Q=f1,K=f2,V=f2  (att1);  z=1: Q=f2,K=f1,V=f1  (att2)
// wave-per-16-rows, wave-local softmax, Q/K/V double-buffered,
// cross-kt V0/Q0 prefetch. grid=(NN/64, NSPLIT, 2).
// LDS: As 8K + KB 16K (Ps 64x128 aliases KB) + Vs 32/16K -> 56/40 KB.
// ---------------------------------------------------------------------------
template <int DIN>
__global__ __launch_bounds__(256, (DIN == 128) ? 3 : 2) void flash_att(
    const us* __restrict__ f1, const us* __restrict__ f2,
    const us* __restrict__ f1T, const us* __restrict__ f2T,
    us* __restrict__ Op, float* __restrict__ mp, float* __restrict__ lp,
    int kvPerSplit) {
  constexpr int NKC = DIN / 32;   // S-phase k chunks
  constexpr int OJ = DIN / 16;    // PV col tiles per wave (full DIN)
  __shared__ alignas(16) us As[2][64 * 32];    // Q dbuf (8 KB)
  __shared__ alignas(16) us KB[2][128 * 32];   // K dbuf (16 KB); Ps alias
  __shared__ alignas(16) us Vs[2][DIN * 32];   // V dbuf
  us* Ps = &KB[0][0];                          // 64 x 128

  const int dir = blockIdx.z;
  const us* Q = dir ? f2 : f1;
  const us* K = dir ? f1 : f2;
  const us* Vt = dir ? f1T : f2T;
  us* Opart = Op + (size_t)dir * NSPLIT * NN * DIN;
  float* mpart = mp + (size_t)dir * NSPLIT * NN;
  float* lpart = lp + (size_t)dir * NSPLIT * NN;

  const int t = threadIdx.x;
  const int wave = t >> 6, lane = t & 63;
  const int wrow = wave * 16;
  const int lrow = lane & 15, quad = lane >> 4;
  const int rowBase = blockIdx.x * 64;
  const int split = blockIdx.y;
  const int kv0 = split * kvPerSplit;
  const int sr = t >> 2, sch = t & 3;
  const int pkey = ((lrow >> 2) ^ lrow) & 3;

  auto stageQ = [&](int kc, int buf) {
    const us* qsrc = Q + (size_t)(rowBase + sr) * DIN + kc * 32 + sch * 8;
    load_lds16(qsrc, (char*)&As[buf][0] + t * 16);
  };
  auto stageK = [&](int kt, int kc, int buf) {
    const us* ksrc = K + (size_t)(kt + sr) * DIN + kc * 32 + sch * 8;
    load_lds16(ksrc, (char*)&KB[buf][0] + t * 16);
    load_lds16(ksrc + (size_t)64 * DIN, (char*)&KB[buf][0] + t * 16 + 4096);
  };
  auto stageV = [&](int kt, int cc, int buf) {
#pragma unroll
    for (int p = 0; p < DIN / 64; p++) {
      const us* vsrc = Vt + (size_t)(p * 64 + sr) * NN + kt + cc * 32 + sch * 8;
      load_lds16(vsrc, (char*)&Vs[buf][0] + p * 4096 + t * 16);
    }
  };

  stageQ(0, 0);
  stageV(kv0, 0, 0);

  float m_i[4], l_i[4];
#pragma unroll
  for (int r = 0; r < 4; r++) { m_i[r] = -3.0e38f; l_i[r] = 0.f; }
  f32x4 accO[OJ];
#pragma unroll
  for (int j = 0; j < OJ; j++) accO[j] = f32x4{0.f, 0.f, 0.f, 0.f};

  for (int kt = kv0; kt < kv0 + kvPerSplit; kt += 128) {
    __syncthreads();                 // E: prev PV's Ps (KB) + Vs reads done
    stageK(kt, 0, 0);

    // ---- Phase 1: S = Q @ K^T (dbuf staging) ----
    f32x4 accS[8];
#pragma unroll
    for (int j = 0; j < 8; j++) accS[j] = f32x4{0.f, 0.f, 0.f, 0.f};
    for (int kc = 0; kc < NKC; kc++) {
      const int buf = kc & 1;
      __syncthreads();               // drain Q/K chunk kc
      if (kc + 1 < NKC) { stageK(kt, kc + 1, buf ^ 1); stageQ(kc + 1, buf ^ 1); }
      bf16x8 af = *(const bf16x8*)&As[buf][(wrow + lrow) * 32 + quad * 8];
#pragma unroll
      for (int j = 0; j < 8; j++) {
        bf16x8 bfr = *(const bf16x8*)&KB[buf][(j * 16 + lrow) * 32 + quad * 8];
        accS[j] = __builtin_amdgcn_mfma_f32_16x16x32_bf16(af, bfr, accS[j], 0, 0, 0);
      }
    }

    // ---- Phase 2: wave-local online softmax (rows wrow..wrow+15) ----
    float alpha[4];
#pragma unroll
    for (int r = 0; r < 4; r++) {
      float v = accS[0][r];
#pragma unroll
      for (int j = 1; j < 8; j++) v = fmaxf(v, accS[j][r]);
#pragma unroll
      for (int mask = 1; mask < 16; mask <<= 1) v = fmaxf(v, __shfl_xor(v, mask));
      float mn = fmaxf(m_i[r], v);
      alpha[r] = __expf(m_i[r] - mn);
      m_i[r] = mn;
    }
    __syncthreads();                 // B1: all KB reads done -> Ps writes safe;
                                     //     also drains V0 (long in flight)
    float ts[4] = {0.f, 0.f, 0.f, 0.f};
#pragma unroll
    for (int j = 0; j < 8; j++)
#pragma unroll
      for (int r = 0; r < 4; r++) {
        float p = __expf(accS[j][r] - m_i[r]);
        ts[r] += p;
        int prow = wrow + quad * 4 + r;
        int key = (quad ^ r) & 3;
        int g = 2 * j + (lrow >> 3);
        Ps[prow * 128 + ((g ^ (key << 1)) << 3) + (lrow & 7)] = f2bf_trunc(p);
      }
#pragma unroll
    for (int r = 0; r < 4; r++) {
      float v = ts[r];
#pragma unroll
      for (int mask = 1; mask < 16; mask <<= 1) v += __shfl_xor(v, mask);
      l_i[r] = l_i[r] * alpha[r] + v;
    }
#pragma unroll
    for (int j = 0; j < OJ; j++)
#pragma unroll
      for (int r = 0; r < 4; r++) accO[j][r] *= alpha[r];

    // ---- Phase 3: O += P @ V (Ps rows wave-private; V dbuf, 4 chunks) ----
    const bool hasNext = (kt + 128 < kv0 + kvPerSplit);
    for (int cc = 0; cc < 4; cc++) {
      if (cc) __syncthreads();       // drain V[cc]
      if (cc + 1 < 4) stageV(kt, cc + 1, (cc + 1) & 1);
      else if (hasNext) { stageV(kt + 128, 0, 0); stageQ(0, 0); }
      const int gk = cc * 4 + quad;
      bf16x8 af = *(const bf16x8*)&Ps[(wrow + lrow) * 128 + ((gk ^ (pkey << 1)) << 3)];
      const us* vb = &Vs[cc & 1][0];
#pragma unroll
      for (int j = 0; j < OJ; j++) {
        bf16x8 bfr = *(const bf16x8*)&vb[(j * 16 + lrow) * 32 + quad * 8];
        accO[j] = __builtin_amdgcn_mfma_f32_16x16x32_bf16(af, bfr, accO[j], 0, 0, 0);
      }
    }
  }

  // ---- epilogue: un-normalized partials ----
#pragma unroll
  for (int j = 0; j < OJ; j++)
#pragma unroll
    for (int r = 0; r < 4; r++) {
      int row = rowBase + wrow + quad * 4 + r;
      int col = j * 16 + lrow;
      Opart[((size_t)split * NN + row) * DIN + col] = f2bf(accO[j][r]);
    }
  if (lrow == 0) {
#pragma unroll
    for (int r = 0; r < 4; r++) {
      int row = rowBase + wrow + quad * 4 + r;
      mpart[(size_t)split * NN + row] = m_i[r];
      lpart[(size_t)split * NN + row] = l_i[r];
    }
  }
}

// fused: merge NSPLIT flash partials + build cat = bf16([c | f | f-att]),
// both directions via blockIdx.z
__global__ void merge_cat(const us* __restrict__ Op, const float* __restrict__ mp,
                          const float* __restrict__ lp,
                          const us* __restrict__ cb1, const us* __restrict__ cb2,
                          const us* __restrict__ f1, const us* __restrict__ f2,
                          us* __restrict__ cat1, us* __restrict__ cat2,
                          int din, int W) {
  const int z = blockIdx.z;
  const us* Ops = Op + (size_t)z * NSPLIT * NN * din;
  const float* mm = mp + (size_t)z * NSPLIT * NN;
  const float* ll = lp + (size_t)z * NSPLIT * NN;
  const us* cbuf = z ? cb2 : cb1;
  const us* fbf = z ? f2 : f1;
  us* cat = z ? cat2 : cat1;
  int i = blockIdx.y;
  int c = blockIdx.x * 256 + threadIdx.x;
  us o;
  if (c < 256) {
    o = cbuf[(size_t)i * 256 + c];
  } else if (c < 256 + din) {
    o = fbf[(size_t)i * din + (c - 256)];
  } else {
    int f = c - 256 - din;
    float m[NSPLIT], w[NSPLIT];
    float M = -3.0e38f;
#pragma unroll
    for (int s = 0; s < NSPLIT; s++) { m[s] = mm[(size_t)s * NN + i]; M = fmaxf(M, m[s]); }
    float L = 0.f;
#pragma unroll
    for (int s = 0; s < NSPLIT; s++) { w[s] = __expf(m[s] - M); L += ll[(size_t)s * NN + i] * w[s]; }
    float a = 0.f;
#pragma unroll
    for (int s = 0; s < NSPLIT; s++)
      a += w[s] * bf2f(Ops[((size_t)s * NN + i) * din + f]);
    o = f2bf(bf2f(fbf[(size_t)i * din + f]) - a / L);
  }
  cat[(size_t)i * W + c] = o;
}

// --------------------------- small kernels ---------------------------------

__global__ void ws_sentinel(float* out) { out[0] = 12345.0f; out[1] = 12345.0f; }

__global__ void cvt2(const float* __restrict__ i1, const float* __restrict__ i2,
                     us* __restrict__ o1, us* __restrict__ o2, int n) {
  const float* in = blockIdx.y ? i2 : i1;
  us* out = blockIdx.y ? o2 : o1;
  int i = (blockIdx.x * 256 + threadIdx.x) * 4;
  if (i < n) {
    f32x4 v = *(const f32x4*)(in + i);
    uint2 p;
    p.x = f2bf(v.x) | ((unsigned)f2bf(v.y) << 16);
    p.y = f2bf(v.z) | ((unsigned)f2bf(v.w) << 16);
    *(uint2*)(out + i) = p;
  }
}

// dst[C][R] = bf16(src[R][C]), fp32 source (single)
__global__ void transpose_bf16(const float* __restrict__ src, us* __restrict__ dst,
                               int R, int C) {
  __shared__ float tile[32][33];
  int c0 = blockIdx.x * 32, r0 = blockIdx.y * 32;
  int x = threadIdx.x, y = threadIdx.y;
  for (int i = y; i < 32; i += 8) tile[i][x] = src[(size_t)(r0 + i) * C + c0 + x];
  __syncthreads();
  for (int i = y; i < 32; i += 8) dst[(size_t)(c0 + i) * R + r0 + x] = f2bf(tile[x][i]);
}

// pair: fp32 source
__global__ void transpose_bf2(const float* __restrict__ s1, const float* __restrict__ s2,
                              us* __restrict__ d1, us* __restrict__ d2, int R, int C) {
  __shared__ float tile[32][33];
  const float* src = blockIdx.z ? s2 : s1;
  us* dst = blockIdx.z ? d2 : d1;
  int c0 = blockIdx.x * 32, r0 = blockIdx.y * 32;
  int x = threadIdx.x, y = threadIdx.y;
  for (int i = y; i < 32; i += 8) tile[i][x] = src[(size_t)(r0 + i) * C + c0 + x];
  __syncthreads();
  for (int i = y; i < 32; i += 8) dst[(size_t)(c0 + i) * R + r0 + x] = f2bf(tile[x][i]);
}

// pair: bf16 source
__global__ void transpose_bb2(const us* __restrict__ s1, const us* __restrict__ s2,
                              us* __restrict__ d1, us* __restrict__ d2, int R, int C) {
  __shared__ us tile[32][33];
  const us* src = blockIdx.z ? s2 : s1;
  us* dst = blockIdx.z ? d2 : d1;
  int c0 = blockIdx.x * 32, r0 = blockIdx.y * 32;
  int x = threadIdx.x, y = threadIdx.y;
  for (int i = y; i < 32; i += 8) tile[i][x] = src[(size_t)(r0 + i) * C + c0 + x];
  __syncthreads();
  for (int i = y; i < 32; i += 8) dst[(size_t)(c0 + i) * R + r0 + x] = tile[x][i];
}

__global__ void deg_count2(const int* __restrict__ d1, const int* __restrict__ d2,
                           int* __restrict__ g1, int* __restrict__ g2) {
  const int* dst = blockIdx.y ? d2 : d1;
  int* deg = blockIdx.y ? g2 : g1;
  int e = blockIdx.x * 256 + threadIdx.x;
  atomicAdd(&deg[dst[e]], 1);
}

__global__ void make_dinv2(const int* __restrict__ g1, const int* __restrict__ g2,
                           float* __restrict__ o1, float* __restrict__ o2) {
  const int* deg = blockIdx.y ? g2 : g1;
  float* dinv = blockIdx.y ? o2 : o1;
  int v = blockIdx.x * 256 + threadIdx.x;
  dinv[v] = rsqrtf((float)(deg[v] + 1));
}

__global__ void scan_deg2(const int* __restrict__ g1, const int* __restrict__ g2,
                          int* __restrict__ r1, int* __restrict__ r2) {
  const int* deg = blockIdx.x ? g2 : g1;
  int* rowstart = blockIdx.x ? r2 : r1;
  __shared__ int part[1024];
  int t = threadIdx.x;
  int base = t * 8;
  int local[8];
  int s = 0;
#pragma unroll
  for (int i = 0; i < 8; i++) { local[i] = s; s += deg[base + i]; }
  part[t] = s;
  __syncthreads();
  for (int off = 1; off < 1024; off <<= 1) {
    int v = (t >= off) ? part[t - off] : 0;
    __syncthreads();
    part[t] += v;
    __syncthreads();
  }
  int offset = (t == 0) ? 0 : part[t - 1];
#pragma unroll
  for (int i = 0; i < 8; i++) rowstart[base + i] = offset + local[i];
  if (t == 1023) rowstart[8192] = offset + s;
}

__global__ void csr_fill2(const int* __restrict__ e1, const int* __restrict__ e2,
                          int* __restrict__ cu1, int* __restrict__ cu2,
                          int* __restrict__ c1, int* __restrict__ c2) {
  const int* ei = blockIdx.y ? e2 : e1;
  int* cursor = blockIdx.y ? cu2 : cu1;
  int* csr_src = blockIdx.y ? c2 : c1;
  int e = blockIdx.x * 256 + threadIdx.x;
  int pos = atomicAdd(&cursor[ei[EDG + e]], 1);
  csr_src[pos] = ei[e];
}

// pair-fused: c[v] = bf16( dinv[v] * (hs[v] + sum_in hs[s]) ); grid (NN/4, 2)
__global__ __launch_bounds__(256) void gcn_agg2(
    const int* __restrict__ r1, const int* __restrict__ r2,
    const int* __restrict__ cs1, const int* __restrict__ cs2,
    const float* __restrict__ d1, const float* __restrict__ d2,
    const us* __restrict__ h1, const us* __restrict__ h2,
    us* __restrict__ o1, us* __restrict__ o2) {
  const int* rowstart = blockIdx.y ? r2 : r1;
  const int* csr_src = blockIdx.y ? cs2 : cs1;
  const float* dinv = blockIdx.y ? d2 : d1;
  const us* hs = blockIdx.y ? h2 : h1;
  us* c = blockIdx.y ? o2 : o1;
  int node = blockIdx.x * 4 + (threadIdx.x >> 6);
  int lane = threadIdx.x & 63;
  const us* hp = hs + lane * 4;
  uint2 u = *(const uint2*)(hp + (size_t)node * 256);
  float a0 = bf2f(u.x & 0xffffu), a1 = bf2f(u.x >> 16);
  float a2 = bf2f(u.y & 0xffffu), a3 = bf2f(u.y >> 16);
  int s0 = rowstart[node], s1 = rowstart[node + 1];
  for (int j = s0; j < s1; j++) {
    int s = csr_src[j];
    uint2 v = *(const uint2*)(hp + (size_t)s * 256);
    a0 += bf2f(v.x & 0xffffu); a1 += bf2f(v.x >> 16);
    a2 += bf2f(v.y & 0xffffu); a3 += bf2f(v.y >> 16);
  }
  float dn = dinv[node];
  uint2 o;
  o.x = f2bf(a0 * dn) | ((unsigned)f2bf(a1 * dn) << 16);
  o.y = f2bf(a2 * dn) | ((unsigned)f2bf(a3 * dn) << 16);
  *(uint2*)(c + (size_t)node * 256 + lane * 4) = o;
}

__global__ void gated_pool2(const float* __restrict__ q1, const float* __restrict__ q2,
                            const us* __restrict__ f1, const us* __restrict__ f2,
                            float* __restrict__ o1, float* __restrict__ o2) {
  const float* q = blockIdx.y ? q2 : q1;
  const us* f = blockIdx.y ? f2 : f1;
  float* p = blockIdx.y ? o2 : o1;
  int col = threadIdx.x;
  int r0 = blockIdx.x * 128;
  float a = 0.f;
  for (int i = r0; i < r0 + 128; i++) {
    float qv = q[(size_t)i * 256 + col];
    a += bf2f(f[(size_t)i * 256 + col]) / (1.f + __expf(-qv));
  }
  atomicAdd(&p[col], a);
}

__global__ void ntn_bilinear(const float* __restrict__ p1, const float* __restrict__ tnW,
                             float* __restrict__ tmp) {
  int c = blockIdx.x * 256 + threadIdx.x;
  float a = 0.f;
#pragma unroll 8
  for (int i = 0; i < 256; i++) a += p1[i] * tnW[(size_t)i * 8192 + c];
  tmp[c] = a;
}

__global__ void ntn_final(const float* __restrict__ tmp, const float* __restrict__ p1,
                          const float* __restrict__ p2, const float* __restrict__ tnWb,
                          const float* __restrict__ tnb, const float* __restrict__ fc1W,
                          const float* __restrict__ fc1b, const float* __restrict__ scW,
                          const float* __restrict__ scb, const float* __restrict__ avgv,
                          float* __restrict__ out) {
  __shared__ float pc[512];
  __shared__ float ntn[32];
  __shared__ float sarr[16];
  int t = threadIdx.x;
  pc[t] = p1[t];
  pc[256 + t] = p2[t];
  __syncthreads();
  if (t < 32) {
    float sc = 0.f;
    for (int j = 0; j < 256; j++) sc += tmp[j * 32 + t] * pc[256 + j];
    float bl = 0.f;
    for (int k = 0; k < 512; k++) bl += tnWb[t * 512 + k] * pc[k];
    float v = sc + bl + tnb[t];
    ntn[t] = v > 0.f ? v : 0.f;
  }
  __syncthreads();
  if (t < 16) {
    float a = fc1b[t];
    for (int i = 0; i < 32; i++) a += ntn[i] * fc1W[i * 16 + t];
    sarr[t] = tanhf(a);
  }
  __syncthreads();
  if (t == 0) {
    float a = scb[0];
    for (int b = 0; b < 16; b++) a += sarr[b] * scW[b];
    float score = 1.f / (1.f + expf(-a));
    out[0] = score;
    out[1] = -logf(score) * avgv[0];
  }
}

// ---------------------------------------------------------------------------

extern "C" void kernel_launch(void* const* d_in, const int* in_sizes, int n_in,
                              void* d_out, int out_size, void* d_ws, size_t ws_size,
                              hipStream_t stream) {
  (void)in_sizes; (void)n_in; (void)out_size;
  const float* feat1 = (const float*)d_in[0];
  const float* feat2 = (const float*)d_in[1];
  const int* ei1 = (const int*)d_in[2];
  const int* ei2 = (const int*)d_in[3];
  const float* avgv = (const float*)d_in[4];
  const float* gcnW[3] = {(const float*)d_in[5], (const float*)d_in[8], (const float*)d_in[11]};
  const float* updW[3] = {(const float*)d_in[6], (const float*)d_in[9], (const float*)d_in[12]};
  const float* updb[3] = {(const float*)d_in[7], (const float*)d_in[10], (const float*)d_in[13]};
  const float* gatedW = (const float*)d_in[14];
  const float* gatedb = (const float*)d_in[15];
  const float* tnW = (const float*)d_in[16];
  const float* tnWb = (const float*)d_in[17];
  const float* tnb = (const float*)d_in[18];
  const float* fc1W = (const float*)d_in[19];
  const float* fc1b = (const float*)d_in[20];
  const float* scW = (const float*)d_in[21];
  const float* scb = (const float*)d_in[22];
  float* out = (float*)d_out;

  char* wp = (char*)d_ws;
  auto take = [&](size_t b) { char* p = wp; wp += (b + 255) & ~(size_t)255; return p; };
  us* Op = (us*)take((size_t)2 * NSPLIT * NN * 256 * 2);       // 32 MB (both dirs)
  us* cat1 = (us*)take((size_t)NN * 768 * 2);                  // 12 MB
  us* cat2 = (us*)take((size_t)NN * 768 * 2);                  // 12 MB
  float* q1 = (float*)cat1;   // gated q aliases cat (cat dead by readout)
  float* q2 = (float*)cat2;
  us* fA1 = (us*)take((size_t)NN * 256 * 2);
  us* fA2 = (us*)take((size_t)NN * 256 * 2);
  us* fB1 = (us*)take((size_t)NN * 256 * 2);
  us* fB2 = (us*)take((size_t)NN * 256 * 2);
  us* f1bT = (us*)take((size_t)NN * 256 * 2);
  us* f2bT = (us*)take((size_t)NN * 256 * 2);
  us* hs1 = (us*)take((size_t)NN * 256 * 2);
  us* hs2 = (us*)take((size_t)NN * 256 * 2);
  us* cb1 = (us*)take((size_t)NN * 256 * 2);
  us* cb2 = (us*)take((size_t)NN * 256 * 2);
  us* WgT[3], *WuT[3];
  for (int l = 0; l < 3; l++) WgT[l] = (us*)take(256 * 256 * 2);
  for (int l = 0; l < 3; l++) WuT[l] = (us*)take(256 * 768 * 2);
  us* gWT = (us*)take(256 * 256 * 2);
  int* deg1 = (int*)take(NN * 4);
  int* deg2 = (int*)take(NN * 4);
  float* dinv1 = (float*)take(NN * 4);
  float* dinv2 = (float*)take(NN * 4);
  int* rs1 = (int*)take((NN + 1) * 4);
  int* rs2 = (int*)take((NN + 1) * 4);
  int* cur1 = (int*)take(NN * 4);
  int* cur2 = (int*)take(NN * 4);
  int* csr1 = (int*)take((size_t)EDG * 4);
  int* csr2 = (int*)take((size_t)EDG * 4);
  float* mp = (float*)take((size_t)2 * NSPLIT * NN * 4);
  float* lp = (float*)take((size_t)2 * NSPLIT * NN * 4);
  float* p1 = (float*)take(1024);
  float* p2 = (float*)take(1024);
  float* tmp = (float*)take(NN * 4);

  size_t need = (size_t)(wp - (char*)d_ws);
  if (need > ws_size) {
    ws_sentinel<<<1, 1, 0, stream>>>(out);
    return;
  }

  // degree / dinv / CSR (edge structure is layer-invariant)
  hipMemsetAsync(deg1, 0, NN * 4, stream);
  hipMemsetAsync(deg2, 0, NN * 4, stream);
  deg_count2<<<dim3(EDG / 256, 2), 256, 0, stream>>>(ei1 + EDG, ei2 + EDG, deg1, deg2);
  make_dinv2<<<dim3(NN / 256, 2), 256, 0, stream>>>(deg1, deg2, dinv1, dinv2);
  scan_deg2<<<2, 1024, 0, stream>>>(deg1, deg2, rs1, rs2);
  hipMemcpyAsync(cur1, rs1, NN * 4, hipMemcpyDeviceToDevice, stream);
  hipMemcpyAsync(cur2, rs2, NN * 4, hipMemcpyDeviceToDevice, stream);
  csr_fill2<<<dim3(EDG / 256, 2), 256, 0, stream>>>(ei1, ei2, cur1, cur2, csr1, csr2);

  // weights -> bf16 [out][in]
  for (int l = 0; l < 3; l++) {
    int din = (l == 0) ? 128 : 256;
    int W = 256 + 2 * din;
    transpose_bf16<<<dim3(8, din / 32), dim3(32, 8), 0, stream>>>(gcnW[l], WgT[l], din, 256);
    transpose_bf16<<<dim3(8, W / 32), dim3(32, 8), 0, stream>>>(updW[l], WuT[l], W, 256);
  }
  transpose_bf16<<<dim3(8, 8), dim3(32, 8), 0, stream>>>(gatedW, gWT, 256, 256);

  // f (bf16) ping-pong
  us* f1 = fA1; us* f2 = fA2;
  us* fn1 = fB1; us* fn2 = fB2;
  cvt2<<<dim3(NN * 128 / 1024, 2), 256, 0, stream>>>(feat1, feat2, f1, f2, NN * 128);

  for (int l = 0; l < 3; l++) {
    const int din = (l == 0) ? 128 : 256;
    const int W = 256 + 2 * din;

    if (l == 0)
      transpose_bf2<<<dim3(din / 32, NN / 32, 2), dim3(32, 8), 0, stream>>>(feat1, feat2, f1bT, f2bT, NN, din);
    else
      transpose_bb2<<<dim3(din / 32, NN / 32, 2), dim3(32, 8), 0, stream>>>(f1, f2, f1bT, f2bT, NN, din);

    // hs = bf16(dinv .* (f @ Wg))
    gemm2<6><<<dim3(128, 2, 2), 256, 0, stream>>>(f1, f2, din, WgT[l], din, dinv1, dinv2, hs1, hs2, 256, din);

    // c = bf16( dinv .* (hs + gather-sum) )
    gcn_agg2<<<dim3(NN / 4, 2), 256, 0, stream>>>(rs1, rs2, csr1, csr2, dinv1, dinv2, hs1, hs2, cb1, cb2);

    // fused flash, both directions; then fused merge+cat
    if (l == 0)
      flash_att<128><<<dim3(NN / 64, NSPLIT, 2), 256, 0, stream>>>(f1, f2, f1bT, f2bT, Op, mp, lp, NN / NSPLIT);
    else
      flash_att<256><<<dim3(NN / 64, NSPLIT, 2), 256, 0, stream>>>(f1, f2, f1bT, f2bT, Op, mp, lp, NN / NSPLIT);
    merge_cat<<<dim3(W / 256, NN, 2), 256, 0, stream>>>(Op, mp, lp, cb1, cb2, f1, f2, cat1, cat2, din, W);

    // g = tanh?(cat @ Wu + bu) -> bf16 directly
    if (l < 2)
      gemm2<5><<<dim3(128, 2, 2), 256, 0, stream>>>(cat1, cat2, W, WuT[l], W, updb[l], updb[l], fn1, fn2, 256, W);
    else
      gemm2<4><<<dim3(128, 2, 2), 256, 0, stream>>>(cat1, cat2, W, WuT[l], W, updb[l], updb[l], fn1, fn2, 256, W);
    us* s;
    s = f1; f1 = fn1; fn1 = s;
    s = f2; f2 = fn2; fn2 = s;
  }

  // gated readout: q = f@gW+gb (fp32, aliases cat), p = sum sigmoid(q)*f
  gemm2<2><<<dim3(128, 2, 2), 256, 0, stream>>>(f1, f2, 256, gWT, 256, gatedb, gatedb, q1, q2, 256, 256);
  hipMemsetAsync(p1, 0, 256 * 4, stream);
  hipMemsetAsync(p2, 0, 256 * 4, stream);
  gated_pool2<<<dim3(64, 2), 256, 0, stream>>>(q1, q2, f1, f2, p1, p2);

  // NTN + scoring head
  ntn_bilinear<<<32, 256, 0, stream>>>(p1, tnW, tmp);
  ntn_final<<<1, 256, 0, stream>>>(tmp, p1, p2, tnWb, tnb, fc1W, fc1b, scW, scb, avgv, out);
}